// Round 10
// baseline (693.610 us; speedup 1.0000x reference)
//
#include <hip/hip_runtime.h>
#include <math.h>

#define G_ 512
#define N_ 512
#define NN_ (G_*N_)
#define EG_ 8192
#define CIN_ 128
#define HID_ 32
#define K_ 20
#define LAT_ 65

// relative tie window: ~1.5 ulp of fp32 (2^-23 = 1.19e-7)
#define EPS_REL 1.8e-7f

// ---------------- CSR build v2: atomic count/place + per-bin sort ----------
__global__ __launch_bounds__(512) void csr2_kernel(const int* __restrict__ src,
                                                   const int* __restrict__ dst,
                                                   unsigned short* __restrict__ srcl,
                                                   int* __restrict__ gstart,
                                                   double* __restrict__ disd) {
    __shared__ int cnt[N_];
    __shared__ int startv[N_];
    __shared__ int tmpv[N_];
    __shared__ int cursor[N_];
    __shared__ unsigned short binE[EG_];
    int g = blockIdx.x, tid = threadIdx.x;
    const int* ds = dst + (size_t)g * EG_;
    const int* ss = src + (size_t)g * EG_;
    int nb = g * N_;

    cnt[tid] = 0;
    __syncthreads();
    for (int e = tid; e < EG_; e += 512) atomicAdd(&cnt[ds[e] - nb], 1);
    __syncthreads();

    startv[tid] = cnt[tid];
    __syncthreads();
    for (int off = 1; off < N_; off <<= 1) {
        tmpv[tid] = startv[tid] + (tid >= off ? startv[tid - off] : 0);
        __syncthreads();
        startv[tid] = tmpv[tid];
        __syncthreads();
    }

    int excl = startv[tid] - cnt[tid];
    cursor[tid] = excl;
    gstart[g * (N_ + 1) + tid] = excl;
    if (tid == 0) gstart[g * (N_ + 1) + N_] = EG_;
    disd[nb + tid] = 1.0 / sqrt((double)(cnt[tid] + 1));
    __syncthreads();

    for (int e = tid; e < EG_; e += 512) {
        int d = ds[e] - nb;
        int slot = atomicAdd(&cursor[d], 1);
        binE[slot] = (unsigned short)e;
    }
    __syncthreads();

    {
        int n = cnt[tid];
        for (int i = 1; i < n; ++i) {
            unsigned short key = binE[excl + i];
            int j = i - 1;
            while (j >= 0 && binE[excl + j] > key) {
                binE[excl + j + 1] = binE[excl + j];
                --j;
            }
            binE[excl + j + 1] = key;
        }
    }
    __syncthreads();

    for (int i = tid; i < EG_; i += 512) {
        int e = binE[i];
        srcl[(size_t)g * EG_ + i] = (unsigned short)(ss[e] - nb);
    }
}

// ---------------- matmul: h[n][o] = sum_c x[n][c]*W[c][o], fp64 acc --------
// 64 nodes/block, 256 threads: thread = (q = tid>>5 -> 8 nodes, o = tid&31).
// Bit-identical chain to the fused version: c ascending, fp64 fma.
template <int CI>
__global__ __launch_bounds__(256) void mm_kernel(const float* __restrict__ xin,
                                                 const float* __restrict__ W,
                                                 double* __restrict__ h) {
    __shared__ float sx[64][CI];        // CI=128: 32 KB
    __shared__ double sWd[CI][HID_];    // CI=128: 32 KB
    int tid = threadIdx.x;
    for (int i = tid; i < CI * HID_; i += 256) sWd[i / HID_][i % HID_] = (double)W[i];
    size_t base = (size_t)blockIdx.x * 64;
    const float4* xsrc = (const float4*)(xin + base * CI);
    float4* dst4 = (float4*)&sx[0][0];
    for (int i = tid; i < 64 * CI / 4; i += 256) dst4[i] = xsrc[i];
    __syncthreads();

    int o = tid & 31, q = tid >> 5;
    int n0 = q * 8;
    double acc[8];
#pragma unroll
    for (int j = 0; j < 8; ++j) acc[j] = 0.0;
    for (int c = 0; c < CI; ++c) {
        double w = sWd[c][o];
#pragma unroll
        for (int j = 0; j < 8; ++j)
            acc[j] = fma((double)sx[n0 + j][c], w, acc[j]);
    }
#pragma unroll
    for (int j = 0; j < 8; ++j)
        h[(base + n0 + j) * HID_ + o] = acc[j];
}

// ---------------- aggregation: reads h (fp64, global), CSR in LDS ----------
// out = tanhf(fp32( a*dn + h[n]*dn^2 + b )) — identical ops/order to fused.
__global__ __launch_bounds__(512) void agg_kernel(const double* __restrict__ h,
                                                  const unsigned short* __restrict__ srcl,
                                                  const int* __restrict__ gstart,
                                                  const double* __restrict__ disd,
                                                  const float* __restrict__ bias,
                                                  float* __restrict__ xoutf) {
    __shared__ unsigned short ssrc[EG_];    // 16 KB
    __shared__ int sstart[N_ + 1];
    __shared__ double sdis[N_];             // 4 KB
    int g = blockIdx.x, tid = threadIdx.x;
    size_t nbase = (size_t)g * N_;

    for (int i = tid; i < EG_; i += 512) ssrc[i] = srcl[(size_t)g * EG_ + i];
    for (int i = tid; i <= N_; i += 512) sstart[i] = gstart[g * (N_ + 1) + i];
    for (int i = tid; i < N_; i += 512) sdis[i] = disd[nbase + i];
    __syncthreads();

    int o = tid & 31, grp = tid >> 5;   // 16 node-groups x 32 channels
    double b = (double)bias[o];
    for (int n = grp; n < N_; n += 16) {
        int e0 = sstart[n], e1 = sstart[n + 1];
        double a = 0.0;
        for (int e = e0; e < e1; ++e) {
            int s = ssrc[e];
            a += h[(nbase + s) * HID_ + o] * sdis[s];
        }
        double dn = sdis[n];
        double v = a * dn + h[(nbase + n) * HID_ + o] * dn * dn + b;
        xoutf[(nbase + n) * HID_ + o] = tanhf((float)v);
    }
}

// ---------------- layer 3 (32 -> 1): fp32 key = round(fp64 tanh) -----------
__global__ __launch_bounds__(512) void gcn3_kernel(const float* __restrict__ xin,
                                                   const float* __restrict__ W2,
                                                   const float* __restrict__ b2,
                                                   const unsigned short* __restrict__ srcl,
                                                   const int* __restrict__ gstart,
                                                   const double* __restrict__ disd,
                                                   float* __restrict__ x3f) {
    __shared__ double h1[N_];
    __shared__ unsigned short ssrc[EG_];
    __shared__ int sstart[N_ + 1];
    __shared__ double sdis[N_];
    int g = blockIdx.x, tid = threadIdx.x;
    size_t nbase = (size_t)g * N_;

    for (int i = tid; i < EG_; i += 512) ssrc[i] = srcl[(size_t)g * EG_ + i];
    for (int i = tid; i <= N_; i += 512) sstart[i] = gstart[g * (N_ + 1) + i];
    int n = tid;
    {
        double a = 0.0;
#pragma unroll
        for (int c = 0; c < HID_; ++c)
            a = fma((double)xin[(nbase + n) * HID_ + c], (double)W2[c], a);
        h1[n] = a;
        sdis[n] = disd[nbase + n];
    }
    __syncthreads();

    int e0 = sstart[n], e1 = sstart[n + 1];
    double a = 0.0;
    for (int e = e0; e < e1; ++e) {
        int s = ssrc[e];
        a += h1[s] * sdis[s];
    }
    double dn = sdis[n];
    double v = a * dn + h1[n] * dn * dn + (double)b2[0];
    x3f[nbase + n] = (float)tanh(v);   // fp32 rank key AND feature value
}

// ---------------- per-graph head: fp32 keys, ulp-window tie -> index -------
__global__ __launch_bounds__(256) void head_kernel(const float* __restrict__ x1,
                                                   const float* __restrict__ x2,
                                                   const float* __restrict__ x3f,
                                                   const float* __restrict__ c1w,
                                                   const float* __restrict__ c1b,
                                                   const float* __restrict__ c2w,
                                                   const float* __restrict__ c2b,
                                                   const float* __restrict__ l1w,
                                                   const float* __restrict__ l1b,
                                                   const float* __restrict__ l2w,
                                                   const float* __restrict__ l2b,
                                                   float* __restrict__ out) {
    int g = blockIdx.x;
    size_t nbase = (size_t)g * N_;
    __shared__ float sv[N_];
    __shared__ int   topk[K_];
    __shared__ float pooled[K_][LAT_];
    __shared__ float c1[16][K_];
    __shared__ float mp[16][10];
    __shared__ float c2[32 * 6];
    __shared__ float l1[128];

    for (int i = threadIdx.x; i < K_; i += 256) topk[i] = i;  // fallback
    for (int i = threadIdx.x; i < N_; i += 256) sv[i] = x3f[nbase + i];
    __syncthreads();

    // top-K descending on fp32 keys; pairs within ~1.5 ulp (relative) are
    // np-fp32 ties -> stable order (lower index first).
    for (int i = threadIdx.x; i < N_; i += 256) {
        float v = sv[i];
        int rank = 0;
        for (int j = 0; j < N_; ++j) {
            float u = sv[j];
            float mag = fmaxf(fabsf(u), fabsf(v));
            bool tie = fabsf(u - v) <= EPS_REL * mag;
            bool beats = tie ? (j < i) : (u > v);
            rank += beats;
        }
        if (rank < K_) topk[rank] = i;
    }
    __syncthreads();

    for (int i = threadIdx.x; i < K_ * LAT_; i += 256) {
        int k = i / LAT_, c = i % LAT_;
        int node = topk[k];
        float f;
        if (c < HID_)            f = x1[(nbase + node) * HID_ + c];
        else if (c < 2 * HID_)   f = x2[(nbase + node) * HID_ + (c - HID_)];
        else                     f = sv[node];
        pooled[k][c] = f;
    }
    __syncthreads();

    for (int i = threadIdx.x; i < 16 * K_; i += 256) {
        int o = i / K_, k = i % K_;
        float acc = c1b[o];
        for (int c = 0; c < LAT_; ++c) acc += pooled[k][c] * c1w[o * LAT_ + c];
        c1[o][k] = fmaxf(acc, 0.f);
    }
    __syncthreads();

    for (int i = threadIdx.x; i < 160; i += 256) {
        int o = i / 10, t = i % 10;
        mp[o][t] = fmaxf(c1[o][2 * t], c1[o][2 * t + 1]);
    }
    __syncthreads();

    for (int i = threadIdx.x; i < 192; i += 256) {
        int o = i / 6, t = i % 6;
        float acc = c2b[o];
        for (int ic = 0; ic < 16; ++ic)
#pragma unroll
            for (int j = 0; j < 5; ++j)
                acc += mp[ic][t + j] * c2w[(o * 16 + ic) * 5 + j];
        c2[o * 6 + t] = fmaxf(acc, 0.f);
    }
    __syncthreads();

    for (int i = threadIdx.x; i < 128; i += 256) {
        float acc = l1b[i];
        for (int c = 0; c < 192; ++c) acc += c2[c] * l1w[c * 128 + i];
        l1[i] = fmaxf(acc, 0.f);
    }
    __syncthreads();

    for (int i = threadIdx.x; i < 2; i += 256) {
        float acc = l2b[i];
        for (int c = 0; c < 128; ++c) acc += l1[c] * l2w[c * 2 + i];
        out[g * 2 + i] = acc;
    }
}

extern "C" void kernel_launch(void* const* d_in, const int* in_sizes, int n_in,
                              void* d_out, int out_size, void* d_ws, size_t ws_size,
                              hipStream_t stream) {
    const float* x   = (const float*)d_in[0];
    const int*   ei  = (const int*)d_in[1];
    const float* W0  = (const float*)d_in[3];
    const float* b0  = (const float*)d_in[4];
    const float* W1  = (const float*)d_in[5];
    const float* b1  = (const float*)d_in[6];
    const float* W2  = (const float*)d_in[7];
    const float* b2  = (const float*)d_in[8];
    const float* c1w = (const float*)d_in[9];
    const float* c1b = (const float*)d_in[10];
    const float* c2w = (const float*)d_in[11];
    const float* c2b = (const float*)d_in[12];
    const float* l1w = (const float*)d_in[13];
    const float* l1b = (const float*)d_in[14];
    const float* l2w = (const float*)d_in[15];
    const float* l2b = (const float*)d_in[16];

    const int* src = ei;
    const int* dst = ei + (size_t)G_ * EG_;

    char* wsb = (char*)d_ws;
    double* h64  = (double*)wsb;                 wsb += (size_t)NN_ * HID_ * 8;     // 64 MiB
    unsigned short* srcl = (unsigned short*)wsb; wsb += (size_t)G_ * EG_ * 2;       // 8 MiB
    int* gstart = (int*)wsb;                     wsb += (size_t)G_ * (N_ + 1) * 4;  // 1 MiB
    double* disd = (double*)wsb;                 wsb += (size_t)NN_ * 8;            // 2 MiB
    float*  x3f  = (float*)wsb;                  wsb += (size_t)NN_ * 4;            // 1 MiB
    float*  x1f  = (float*)wsb;                  wsb += (size_t)NN_ * HID_ * 4;     // 32 MiB
    float*  x2f  = (float*)wsb;                  wsb += (size_t)NN_ * HID_ * 4;     // 32 MiB

    csr2_kernel<<<G_, 512, 0, stream>>>(src, dst, srcl, gstart, disd);
    mm_kernel<CIN_><<<NN_ / 64, 256, 0, stream>>>(x, W0, h64);
    agg_kernel<<<G_, 512, 0, stream>>>(h64, srcl, gstart, disd, b0, x1f);
    mm_kernel<HID_><<<NN_ / 64, 256, 0, stream>>>(x1f, W1, h64);
    agg_kernel<<<G_, 512, 0, stream>>>(h64, srcl, gstart, disd, b1, x2f);
    gcn3_kernel<<<G_, 512, 0, stream>>>(x2f, W2, b2, srcl, gstart, disd, x3f);
    head_kernel<<<G_, 256, 0, stream>>>(x1f, x2f, x3f, c1w, c1b, c2w, c2b,
                                        l1w, l1b, l2w, l2b, (float*)d_out);
}

// Round 11
// 473.693 us; speedup vs baseline: 1.4643x; 1.4643x over previous
//
#include <hip/hip_runtime.h>
#include <math.h>

#define G_ 512
#define N_ 512
#define NN_ (G_*N_)
#define EG_ 8192
#define CIN_ 128
#define HID_ 32
#define K_ 20
#define LAT_ 65

// relative tie window: ~1.5 ulp of fp32 (2^-23 = 1.19e-7)
#define EPS_REL 1.8e-7f

// ---------------- CSR build v2: atomic count/place + per-bin sort ----------
__global__ __launch_bounds__(512) void csr2_kernel(const int* __restrict__ src,
                                                   const int* __restrict__ dst,
                                                   unsigned short* __restrict__ srcl,
                                                   int* __restrict__ gstart,
                                                   double* __restrict__ disd) {
    __shared__ int cnt[N_];
    __shared__ int startv[N_];
    __shared__ int tmpv[N_];
    __shared__ int cursor[N_];
    __shared__ unsigned short binE[EG_];
    int g = blockIdx.x, tid = threadIdx.x;
    const int* ds = dst + (size_t)g * EG_;
    const int* ss = src + (size_t)g * EG_;
    int nb = g * N_;

    cnt[tid] = 0;
    __syncthreads();
    for (int e = tid; e < EG_; e += 512) atomicAdd(&cnt[ds[e] - nb], 1);
    __syncthreads();

    startv[tid] = cnt[tid];
    __syncthreads();
    for (int off = 1; off < N_; off <<= 1) {
        tmpv[tid] = startv[tid] + (tid >= off ? startv[tid - off] : 0);
        __syncthreads();
        startv[tid] = tmpv[tid];
        __syncthreads();
    }

    int excl = startv[tid] - cnt[tid];
    cursor[tid] = excl;
    gstart[g * (N_ + 1) + tid] = excl;
    if (tid == 0) gstart[g * (N_ + 1) + N_] = EG_;
    disd[nb + tid] = 1.0 / sqrt((double)(cnt[tid] + 1));
    __syncthreads();

    for (int e = tid; e < EG_; e += 512) {
        int d = ds[e] - nb;
        int slot = atomicAdd(&cursor[d], 1);
        binE[slot] = (unsigned short)e;
    }
    __syncthreads();

    {
        int n = cnt[tid];
        for (int i = 1; i < n; ++i) {
            unsigned short key = binE[excl + i];
            int j = i - 1;
            while (j >= 0 && binE[excl + j] > key) {
                binE[excl + j + 1] = binE[excl + j];
                --j;
            }
            binE[excl + j + 1] = key;
        }
    }
    __syncthreads();

    for (int i = tid; i < EG_; i += 512) {
        int e = binE[i];
        srcl[(size_t)g * EG_ + i] = (unsigned short)(ss[e] - nb);
    }
}

// ---------------- matmul: h[n][o] = sum_c x[n][c]*W[c][o], fp64 acc --------
// 64 nodes/block, 256 threads: thread = (q = tid>>5 -> 8 nodes, o = tid&31).
template <int CI>
__global__ __launch_bounds__(256) void mm_kernel(const float* __restrict__ xin,
                                                 const float* __restrict__ W,
                                                 double* __restrict__ h) {
    __shared__ float sx[64][CI];        // CI=128: 32 KB
    __shared__ double sWd[CI][HID_];    // CI=128: 32 KB
    int tid = threadIdx.x;
    for (int i = tid; i < CI * HID_; i += 256) sWd[i / HID_][i % HID_] = (double)W[i];
    size_t base = (size_t)blockIdx.x * 64;
    const float4* xsrc = (const float4*)(xin + base * CI);
    float4* dst4 = (float4*)&sx[0][0];
    for (int i = tid; i < 64 * CI / 4; i += 256) dst4[i] = xsrc[i];
    __syncthreads();

    int o = tid & 31, q = tid >> 5;
    int n0 = q * 8;
    double acc[8];
#pragma unroll
    for (int j = 0; j < 8; ++j) acc[j] = 0.0;
    for (int c = 0; c < CI; ++c) {
        double w = sWd[c][o];
#pragma unroll
        for (int j = 0; j < 8; ++j)
            acc[j] = fma((double)sx[n0 + j][c], w, acc[j]);
    }
#pragma unroll
    for (int j = 0; j < 8; ++j)
        h[(base + n0 + j) * HID_ + o] = acc[j];
}

// ---------------- aggregation: h graph-slab staged in LDS ----------------
// out = tanhf(fp32( a*dn + h[n]*dn^2 + b )) — ops/order identical to r10.
__global__ __launch_bounds__(512) void agg_lds_kernel(const double* __restrict__ h,
                                                      const unsigned short* __restrict__ srcl,
                                                      const int* __restrict__ gstart,
                                                      const double* __restrict__ disd,
                                                      const float* __restrict__ bias,
                                                      float* __restrict__ xoutf) {
    __shared__ double hd[N_ * HID_];        // 128 KB
    __shared__ unsigned short ssrc[EG_];    // 16 KB
    __shared__ int sstart[N_ + 1];
    __shared__ double sdis[N_];             // 4 KB
    int g = blockIdx.x, tid = threadIdx.x;
    size_t nbase = (size_t)g * N_;

    const double2* hsrc = (const double2*)(h + nbase * HID_);
    double2* hdst = (double2*)hd;
    for (int i = tid; i < N_ * HID_ / 2; i += 512) hdst[i] = hsrc[i];
    for (int i = tid; i < EG_; i += 512) ssrc[i] = srcl[(size_t)g * EG_ + i];
    for (int i = tid; i <= N_; i += 512) sstart[i] = gstart[g * (N_ + 1) + i];
    for (int i = tid; i < N_; i += 512) sdis[i] = disd[nbase + i];
    __syncthreads();

    int o = tid & 31, grp = tid >> 5;   // 16 node-groups x 32 channels
    double b = (double)bias[o];
    for (int n = grp; n < N_; n += 16) {
        int e0 = sstart[n], e1 = sstart[n + 1];
        double a = 0.0;
        for (int e = e0; e < e1; ++e) {
            int s = ssrc[e];
            a += hd[s * HID_ + o] * sdis[s];
        }
        double dn = sdis[n];
        double v = a * dn + hd[n * HID_ + o] * dn * dn + b;
        xoutf[(nbase + n) * HID_ + o] = tanhf((float)v);
    }
}

// ---------------- layer 3 (32 -> 1): fp32 key = round(fp64 tanh) -----------
__global__ __launch_bounds__(512) void gcn3_kernel(const float* __restrict__ xin,
                                                   const float* __restrict__ W2,
                                                   const float* __restrict__ b2,
                                                   const unsigned short* __restrict__ srcl,
                                                   const int* __restrict__ gstart,
                                                   const double* __restrict__ disd,
                                                   float* __restrict__ x3f) {
    __shared__ double h1[N_];
    __shared__ unsigned short ssrc[EG_];
    __shared__ int sstart[N_ + 1];
    __shared__ double sdis[N_];
    int g = blockIdx.x, tid = threadIdx.x;
    size_t nbase = (size_t)g * N_;

    for (int i = tid; i < EG_; i += 512) ssrc[i] = srcl[(size_t)g * EG_ + i];
    for (int i = tid; i <= N_; i += 512) sstart[i] = gstart[g * (N_ + 1) + i];
    int n = tid;
    {
        double a = 0.0;
#pragma unroll
        for (int c = 0; c < HID_; ++c)
            a = fma((double)xin[(nbase + n) * HID_ + c], (double)W2[c], a);
        h1[n] = a;
        sdis[n] = disd[nbase + n];
    }
    __syncthreads();

    int e0 = sstart[n], e1 = sstart[n + 1];
    double a = 0.0;
    for (int e = e0; e < e1; ++e) {
        int s = ssrc[e];
        a += h1[s] * sdis[s];
    }
    double dn = sdis[n];
    double v = a * dn + h1[n] * dn * dn + (double)b2[0];
    x3f[nbase + n] = (float)tanh(v);   // fp32 rank key AND feature value
}

// ---------------- per-graph head: fp32 keys, ulp-window tie -> index -------
__global__ __launch_bounds__(256) void head_kernel(const float* __restrict__ x1,
                                                   const float* __restrict__ x2,
                                                   const float* __restrict__ x3f,
                                                   const float* __restrict__ c1w,
                                                   const float* __restrict__ c1b,
                                                   const float* __restrict__ c2w,
                                                   const float* __restrict__ c2b,
                                                   const float* __restrict__ l1w,
                                                   const float* __restrict__ l1b,
                                                   const float* __restrict__ l2w,
                                                   const float* __restrict__ l2b,
                                                   float* __restrict__ out) {
    int g = blockIdx.x;
    size_t nbase = (size_t)g * N_;
    __shared__ float sv[N_];
    __shared__ int   topk[K_];
    __shared__ float pooled[K_][LAT_];
    __shared__ float c1[16][K_];
    __shared__ float mp[16][10];
    __shared__ float c2[32 * 6];
    __shared__ float l1[128];

    for (int i = threadIdx.x; i < K_; i += 256) topk[i] = i;  // fallback
    for (int i = threadIdx.x; i < N_; i += 256) sv[i] = x3f[nbase + i];
    __syncthreads();

    // top-K descending on fp32 keys; pairs within ~1.5 ulp (relative) are
    // np-fp32 ties -> stable order (lower index first).
    for (int i = threadIdx.x; i < N_; i += 256) {
        float v = sv[i];
        int rank = 0;
        for (int j = 0; j < N_; ++j) {
            float u = sv[j];
            float mag = fmaxf(fabsf(u), fabsf(v));
            bool tie = fabsf(u - v) <= EPS_REL * mag;
            bool beats = tie ? (j < i) : (u > v);
            rank += beats;
        }
        if (rank < K_) topk[rank] = i;
    }
    __syncthreads();

    for (int i = threadIdx.x; i < K_ * LAT_; i += 256) {
        int k = i / LAT_, c = i % LAT_;
        int node = topk[k];
        float f;
        if (c < HID_)            f = x1[(nbase + node) * HID_ + c];
        else if (c < 2 * HID_)   f = x2[(nbase + node) * HID_ + (c - HID_)];
        else                     f = sv[node];
        pooled[k][c] = f;
    }
    __syncthreads();

    for (int i = threadIdx.x; i < 16 * K_; i += 256) {
        int o = i / K_, k = i % K_;
        float acc = c1b[o];
        for (int c = 0; c < LAT_; ++c) acc += pooled[k][c] * c1w[o * LAT_ + c];
        c1[o][k] = fmaxf(acc, 0.f);
    }
    __syncthreads();

    for (int i = threadIdx.x; i < 160; i += 256) {
        int o = i / 10, t = i % 10;
        mp[o][t] = fmaxf(c1[o][2 * t], c1[o][2 * t + 1]);
    }
    __syncthreads();

    for (int i = threadIdx.x; i < 192; i += 256) {
        int o = i / 6, t = i % 6;
        float acc = c2b[o];
        for (int ic = 0; ic < 16; ++ic)
#pragma unroll
            for (int j = 0; j < 5; ++j)
                acc += mp[ic][t + j] * c2w[(o * 16 + ic) * 5 + j];
        c2[o * 6 + t] = fmaxf(acc, 0.f);
    }
    __syncthreads();

    for (int i = threadIdx.x; i < 128; i += 256) {
        float acc = l1b[i];
        for (int c = 0; c < 192; ++c) acc += c2[c] * l1w[c * 128 + i];
        l1[i] = fmaxf(acc, 0.f);
    }
    __syncthreads();

    for (int i = threadIdx.x; i < 2; i += 256) {
        float acc = l2b[i];
        for (int c = 0; c < 128; ++c) acc += l1[c] * l2w[c * 2 + i];
        out[g * 2 + i] = acc;
    }
}

extern "C" void kernel_launch(void* const* d_in, const int* in_sizes, int n_in,
                              void* d_out, int out_size, void* d_ws, size_t ws_size,
                              hipStream_t stream) {
    const float* x   = (const float*)d_in[0];
    const int*   ei  = (const int*)d_in[1];
    const float* W0  = (const float*)d_in[3];
    const float* b0  = (const float*)d_in[4];
    const float* W1  = (const float*)d_in[5];
    const float* b1  = (const float*)d_in[6];
    const float* W2  = (const float*)d_in[7];
    const float* b2  = (const float*)d_in[8];
    const float* c1w = (const float*)d_in[9];
    const float* c1b = (const float*)d_in[10];
    const float* c2w = (const float*)d_in[11];
    const float* c2b = (const float*)d_in[12];
    const float* l1w = (const float*)d_in[13];
    const float* l1b = (const float*)d_in[14];
    const float* l2w = (const float*)d_in[15];
    const float* l2b = (const float*)d_in[16];

    const int* src = ei;
    const int* dst = ei + (size_t)G_ * EG_;

    char* wsb = (char*)d_ws;
    double* h64  = (double*)wsb;                 wsb += (size_t)NN_ * HID_ * 8;     // 64 MiB
    unsigned short* srcl = (unsigned short*)wsb; wsb += (size_t)G_ * EG_ * 2;       // 8 MiB
    int* gstart = (int*)wsb;                     wsb += (size_t)G_ * (N_ + 1) * 4;  // 1 MiB
    double* disd = (double*)wsb;                 wsb += (size_t)NN_ * 8;            // 2 MiB
    float*  x3f  = (float*)wsb;                  wsb += (size_t)NN_ * 4;            // 1 MiB
    float*  x1f  = (float*)wsb;                  wsb += (size_t)NN_ * HID_ * 4;     // 32 MiB
    float*  x2f  = (float*)wsb;                  wsb += (size_t)NN_ * HID_ * 4;     // 32 MiB

    csr2_kernel<<<G_, 512, 0, stream>>>(src, dst, srcl, gstart, disd);
    mm_kernel<CIN_><<<NN_ / 64, 256, 0, stream>>>(x, W0, h64);
    agg_lds_kernel<<<G_, 512, 0, stream>>>(h64, srcl, gstart, disd, b0, x1f);
    mm_kernel<HID_><<<NN_ / 64, 256, 0, stream>>>(x1f, W1, h64);
    agg_lds_kernel<<<G_, 512, 0, stream>>>(h64, srcl, gstart, disd, b1, x2f);
    gcn3_kernel<<<G_, 512, 0, stream>>>(x2f, W2, b2, srcl, gstart, disd, x3f);
    head_kernel<<<G_, 256, 0, stream>>>(x1f, x2f, x3f, c1w, c1b, c2w, c2b,
                                        l1w, l1b, l2w, l2b, (float*)d_out);
}